// Round 1
// baseline (2501.508 us; speedup 1.0000x reference)
//
#include <hip/hip_runtime.h>

#define K_OFF 27
#define NDOWN 40000
#define NUP   160000
#define CDOWN 128
#define CSKIP 64
#define CCAT  192
#define COUT  96
#define TM    64

typedef __bf16 bf16x8 __attribute__((ext_vector_type(8)));
typedef float f32x4 __attribute__((ext_vector_type(4)));

__device__ __forceinline__ unsigned short f2b(float f) {
    unsigned int u = __float_as_uint(f);
    u += 0x7FFFu + ((u >> 16) & 1u);           // round-to-nearest-even
    return (unsigned short)(u >> 16);
}

// ---------------- Deconv: up[out_idx[k][i]] += down[in_idx[k][i]] @ Wd[k] ----------------
#define SA1 136   // 128 + 8 pad (stride 272B -> +4 banks/row, 2-way alias = free)
#define SB1 136

__global__ __launch_bounds__(256, 2)
void deconv_kernel(const float* __restrict__ down,
                   const float* __restrict__ Wd,
                   const int* __restrict__ in_idx,
                   const int* __restrict__ out_idx,
                   float* __restrict__ up) {
    __shared__ __align__(16) unsigned short sA[TM * SA1];     // A tile [64][128] bf16
    __shared__ __align__(16) unsigned short sB[CDOWN * SB1];  // W^T  [n][k]  bf16
    __shared__ int sOut[TM];

    const int tiles = NDOWN / TM;            // 625
    const int bk = blockIdx.x / tiles;       // kernel offset 0..26
    const int tile = blockIdx.x % tiles;
    const int t = threadIdx.x;
    const long kInBase = (long)bk * NDOWN + tile * TM;

    // stage A: gather 64 rows of down_feat, cvt bf16
    {
        const int r = t >> 2;
        const int c0 = (t & 3) * 32;
        const int j = in_idx[kInBase + r];
        const float* src = down + (long)j * CDOWN + c0;
        unsigned short* dst = sA + r * SA1 + c0;
        #pragma unroll
        for (int c = 0; c < 32; c += 4) {
            float4 v = *(const float4*)(src + c);
            *(unsigned int*)(dst + c)     = (unsigned)f2b(v.x) | ((unsigned)f2b(v.y) << 16);
            *(unsigned int*)(dst + c + 2) = (unsigned)f2b(v.z) | ((unsigned)f2b(v.w) << 16);
        }
    }
    // stage B transposed: sB[n][kk] = Wd[bk][kk][n]
    {
        const float* wsrc = Wd + (long)bk * CDOWN * CDOWN;
        for (int idx = t; idx < CDOWN * CDOWN; idx += 256) {
            const int kk = idx >> 7;
            const int n  = idx & 127;
            sB[n * SB1 + kk] = f2b(wsrc[idx]);
        }
    }
    if (t < TM) sOut[t] = out_idx[kInBase + t];
    __syncthreads();

    const int wave = t >> 6;
    const int lane = t & 63;
    const int col  = lane & 15;
    const int quad = lane >> 4;
    const int mrow = wave * 16 + col;        // A-operand row for this lane

    f32x4 acc[8];
    #pragma unroll
    for (int i = 0; i < 8; i++) acc[i] = (f32x4){0.f, 0.f, 0.f, 0.f};

    #pragma unroll
    for (int k0 = 0; k0 < CDOWN; k0 += 32) {
        const int koff = k0 + quad * 8;
        bf16x8 a = *(const bf16x8*)&sA[mrow * SA1 + koff];
        #pragma unroll
        for (int nt = 0; nt < 8; nt++) {
            bf16x8 b = *(const bf16x8*)&sB[(nt * 16 + col) * SB1 + koff];
            acc[nt] = __builtin_amdgcn_mfma_f32_16x16x32_bf16(a, b, acc[nt], 0, 0, 0);
        }
    }

    // scatter-add: C/D layout col=lane&15, row=quad*4+reg
    #pragma unroll
    for (int r = 0; r < 4; r++) {
        const int lrow = wave * 16 + quad * 4 + r;
        const long obase = (long)sOut[lrow] * CDOWN;
        #pragma unroll
        for (int nt = 0; nt < 8; nt++)
            atomicAdd(&up[obase + nt * 16 + col], acc[nt][r]);
    }
}

// ---- Conv: out[cout_idx[k][i]] += concat(relu(up),skip)[cin_idx[k][i]] @ Wc[k] ----
#define SA2 200   // 192 + 8 pad
#define SB2 200

__global__ __launch_bounds__(256, 2)
void conv_kernel(const float* __restrict__ up,
                 const float* __restrict__ skip,
                 const float* __restrict__ Wc,
                 const int* __restrict__ in_idx,
                 const int* __restrict__ out_idx,
                 float* __restrict__ out) {
    __shared__ __align__(16) unsigned short sA[TM * SA2];     // cat tile [64][192]
    __shared__ __align__(16) unsigned short sB[COUT * SB2];   // Wc^T [n][k]
    __shared__ int sOut[TM];

    const int tiles = NUP / TM;              // 2500
    const int bk = blockIdx.x / tiles;
    const int tile = blockIdx.x % tiles;
    const int t = threadIdx.x;
    const long kInBase = (long)bk * NUP + tile * TM;

    // stage A: gather rows, fusing relu(up) ++ skip
    {
        const int r = t >> 2;
        const int c0 = (t & 3) * 48;
        const int j = in_idx[kInBase + r];
        const float* uprow = up + (long)j * CDOWN;
        const float* skrow = skip + (long)j * CSKIP;
        unsigned short* dst = sA + r * SA2 + c0;
        #pragma unroll
        for (int c = 0; c < 48; c += 4) {
            const int gc = c0 + c;
            float4 v;
            if (gc < CDOWN) {
                v = *(const float4*)(uprow + gc);
                v.x = fmaxf(v.x, 0.f); v.y = fmaxf(v.y, 0.f);
                v.z = fmaxf(v.z, 0.f); v.w = fmaxf(v.w, 0.f);
            } else {
                v = *(const float4*)(skrow + (gc - CDOWN));
            }
            *(unsigned int*)(dst + c)     = (unsigned)f2b(v.x) | ((unsigned)f2b(v.y) << 16);
            *(unsigned int*)(dst + c + 2) = (unsigned)f2b(v.z) | ((unsigned)f2b(v.w) << 16);
        }
    }
    // stage B transposed: sB[n][kk] = Wc[bk][kk][n]
    {
        const float* wsrc = Wc + (long)bk * CCAT * COUT;
        for (int idx = t; idx < CCAT * COUT; idx += 256) {
            const int kk = idx / COUT;
            const int n  = idx - kk * COUT;
            sB[n * SB2 + kk] = f2b(wsrc[idx]);
        }
    }
    if (t < TM) sOut[t] = out_idx[kInBase + t];
    __syncthreads();

    const int wave = t >> 6;
    const int lane = t & 63;
    const int col  = lane & 15;
    const int quad = lane >> 4;
    const int mrow = wave * 16 + col;

    f32x4 acc[6];
    #pragma unroll
    for (int i = 0; i < 6; i++) acc[i] = (f32x4){0.f, 0.f, 0.f, 0.f};

    #pragma unroll
    for (int k0 = 0; k0 < CCAT; k0 += 32) {
        const int koff = k0 + quad * 8;
        bf16x8 a = *(const bf16x8*)&sA[mrow * SA2 + koff];
        #pragma unroll
        for (int nt = 0; nt < 6; nt++) {
            bf16x8 b = *(const bf16x8*)&sB[(nt * 16 + col) * SB2 + koff];
            acc[nt] = __builtin_amdgcn_mfma_f32_16x16x32_bf16(a, b, acc[nt], 0, 0, 0);
        }
    }

    #pragma unroll
    for (int r = 0; r < 4; r++) {
        const int lrow = wave * 16 + quad * 4 + r;
        const long obase = (long)sOut[lrow] * COUT;
        #pragma unroll
        for (int nt = 0; nt < 6; nt++)
            atomicAdd(&out[obase + nt * 16 + col], acc[nt][r]);
    }
}

// ---------------- final ReLU on out ----------------
__global__ void relu_kernel(float* __restrict__ x, int n4) {
    int i = blockIdx.x * blockDim.x + threadIdx.x;
    if (i < n4) {
        float4 v = ((float4*)x)[i];
        v.x = fmaxf(v.x, 0.f); v.y = fmaxf(v.y, 0.f);
        v.z = fmaxf(v.z, 0.f); v.w = fmaxf(v.w, 0.f);
        ((float4*)x)[i] = v;
    }
}

extern "C" void kernel_launch(void* const* d_in, const int* in_sizes, int n_in,
                              void* d_out, int out_size, void* d_ws, size_t ws_size,
                              hipStream_t stream) {
    const float* skip   = (const float*)d_in[0];
    const float* down   = (const float*)d_in[1];
    const float* Wd     = (const float*)d_in[2];
    const float* Wc     = (const float*)d_in[3];
    const int* dc_in    = (const int*)d_in[4];
    const int* dc_out   = (const int*)d_in[5];
    const int* cv_in    = (const int*)d_in[6];
    const int* cv_out   = (const int*)d_in[7];
    float* out = (float*)d_out;
    float* up  = (float*)d_ws;   // [NUP][CDOWN] f32 accumulator, 81.92 MB

    hipMemsetAsync(up, 0, (size_t)NUP * CDOWN * sizeof(float), stream);
    hipMemsetAsync(out, 0, (size_t)out_size * sizeof(float), stream);

    deconv_kernel<<<K_OFF * (NDOWN / TM), 256, 0, stream>>>(down, Wd, dc_in, dc_out, up);
    conv_kernel<<<K_OFF * (NUP / TM), 256, 0, stream>>>(up, skip, Wc, cv_in, cv_out, out);
    relu_kernel<<<(out_size / 4 + 255) / 256, 256, 0, stream>>>(out, out_size / 4);
}